// Round 1
// baseline (4611.185 us; speedup 1.0000x reference)
//
#include <hip/hip_runtime.h>
#include <cstdint>
#include <cstddef>

#define UNITS 25
#define GATES 100   // 4*25, order: i | f | c | o
#define IN_DIM 64
#define BATCH 256
#define SEQ 2048

__device__ __forceinline__ float sigmoidf_(float x) {
    return 1.0f / (1.0f + __expf(-x));
}
__device__ __forceinline__ float tanhf_(float x) {
    // tanh(x) = 2/(1+exp(-2x)) - 1 ; saturates correctly for large |x|
    return 2.0f / (1.0f + __expf(-2.0f * x)) - 1.0f;
}

// ---------------------------------------------------------------------------
// Kernel A: pre1[row, col] = b[col] + x[row,:] @ Wx[:, col]   (row = b*SEQ+t)
// col in [0,100): gate g = col/25, unit u = col%25.
// Mapping: gid = blockIdx*256 + tid; row = gid>>7; col = gid&127 (col>=100 idle)
// ---------------------------------------------------------------------------
__global__ __launch_bounds__(256)
void proj1_kernel(const float* __restrict__ x,
                  const float* __restrict__ Wxi, const float* __restrict__ bi,
                  const float* __restrict__ Wxf, const float* __restrict__ bf,
                  const float* __restrict__ Wxc, const float* __restrict__ bc,
                  const float* __restrict__ Wxo, const float* __restrict__ bo,
                  float* __restrict__ pre) {
    const long long gid = (long long)blockIdx.x * blockDim.x + threadIdx.x;
    const long long row = gid >> 7;
    const int col = (int)(gid & 127);
    if (row >= (long long)BATCH * SEQ) return;
    if (col >= GATES) return;
    const int g = col / UNITS;
    const int u = col - g * UNITS;
    const float* W  = (g == 0) ? Wxi : (g == 1) ? Wxf : (g == 2) ? Wxc : Wxo;
    const float* bv = (g == 0) ? bi  : (g == 1) ? bf  : (g == 2) ? bc  : bo;
    const float* xr = x + row * IN_DIM;
    float acc = bv[u];
    #pragma unroll
    for (int k = 0; k < IN_DIM; ++k) {
        acc = fmaf(xr[k], W[k * UNITS + u], acc);
    }
    pre[row * GATES + col] = acc;
}

// ---------------------------------------------------------------------------
// Kernel B: fused 2-layer LSTM scan + output head. One batch element per block.
// 128 threads: tid<100 compute gates (one column each, weights in VGPRs),
// tid<25 own unit state (c1,c2 in registers; h1,h2 broadcast via LDS).
// 3 __syncthreads per timestep (hazard graph verified: none needed after D).
// ---------------------------------------------------------------------------
template<bool USE_PRE>
__global__ __launch_bounds__(128, 1)
void lstm_seq_kernel(const float* __restrict__ x,
                     const float* __restrict__ pre,
                     const float* __restrict__ l1_Whi, const float* __restrict__ l1_Whf,
                     const float* __restrict__ l1_Whc, const float* __restrict__ l1_Who,
                     const float* __restrict__ l1_bi,  const float* __restrict__ l1_bf,
                     const float* __restrict__ l1_bc,  const float* __restrict__ l1_bo,
                     const float* __restrict__ l1_Wxi, const float* __restrict__ l1_Wxf,
                     const float* __restrict__ l1_Wxc, const float* __restrict__ l1_Wxo,
                     const float* __restrict__ l2_Wxi, const float* __restrict__ l2_Wxf,
                     const float* __restrict__ l2_Wxc, const float* __restrict__ l2_Wxo,
                     const float* __restrict__ l2_Whi, const float* __restrict__ l2_Whf,
                     const float* __restrict__ l2_Whc, const float* __restrict__ l2_Who,
                     const float* __restrict__ l2_bi,  const float* __restrict__ l2_bf,
                     const float* __restrict__ l2_bc,  const float* __restrict__ l2_bo,
                     const float* __restrict__ Wout,   const float* __restrict__ bout,
                     float* __restrict__ out) {
    const int b   = blockIdx.x;
    const int tid = threadIdx.x;
    const int g = tid / UNITS;          // 0..3 for tid<100
    const int u = tid - g * UNITS;

    __shared__ float h1s[UNITS];
    __shared__ float h2s[UNITS];
    __shared__ float g1s[GATES];
    __shared__ float g2s[GATES];
    __shared__ float xs[2][IN_DIM];     // only used when !USE_PRE

    float wh1[UNITS], wx2[UNITS], wh2[UNITS];
    float wx1[IN_DIM];                  // only used when !USE_PRE
    float b1r = 0.f, b2r = 0.f;

    if (tid < GATES) {
        const float* Wh1 = (g==0)? l1_Whi : (g==1)? l1_Whf : (g==2)? l1_Whc : l1_Who;
        const float* Wx2 = (g==0)? l2_Wxi : (g==1)? l2_Wxf : (g==2)? l2_Wxc : l2_Wxo;
        const float* Wh2 = (g==0)? l2_Whi : (g==1)? l2_Whf : (g==2)? l2_Whc : l2_Who;
        #pragma unroll
        for (int k = 0; k < UNITS; ++k) {
            wh1[k] = Wh1[k*UNITS + u];
            wx2[k] = Wx2[k*UNITS + u];
            wh2[k] = Wh2[k*UNITS + u];
        }
        const float* b2p = (g==0)? l2_bi : (g==1)? l2_bf : (g==2)? l2_bc : l2_bo;
        b2r = b2p[u];
        if (!USE_PRE) {
            const float* Wx1 = (g==0)? l1_Wxi : (g==1)? l1_Wxf : (g==2)? l1_Wxc : l1_Wxo;
            #pragma unroll
            for (int k = 0; k < IN_DIM; ++k) wx1[k] = Wx1[k*UNITS + u];
            const float* b1p = (g==0)? l1_bi : (g==1)? l1_bf : (g==2)? l1_bc : l1_bo;
            b1r = b1p[u];
        }
    }
    const float woutr = (tid < UNITS) ? Wout[tid] : 0.f;
    const float boutv = bout[0];
    float c1 = 0.f, c2 = 0.f;
    if (tid < UNITS) { h1s[tid] = 0.f; h2s[tid] = 0.f; }
    if (!USE_PRE) {
        if (tid < IN_DIM) xs[0][tid] = x[((size_t)b * SEQ + 0) * IN_DIM + tid];
    }
    __syncthreads();

    float preval = 0.f;
    if (USE_PRE) {
        if (tid < GATES) preval = pre[((size_t)b * SEQ + 0) * GATES + tid];
    }

    for (int t = 0; t < SEQ; ++t) {
        // ---- prefetch / stage next timestep input (off the dependency chain)
        float prenext = 0.f;
        if (USE_PRE) {
            if (tid < GATES && t + 1 < SEQ)
                prenext = pre[((size_t)b * SEQ + (t + 1)) * GATES + tid];
        } else {
            if (tid < IN_DIM && t + 1 < SEQ)
                xs[(t + 1) & 1][tid] = x[((size_t)b * SEQ + (t + 1)) * IN_DIM + tid];
        }

        // ---- Phase A: layer-1 gate pre-activations
        if (tid < GATES) {
            float a;
            if (USE_PRE) {
                a = preval;
            } else {
                a = b1r;
                const float* xcur = xs[t & 1];
                #pragma unroll
                for (int k = 0; k < IN_DIM; ++k) a = fmaf(xcur[k], wx1[k], a);
            }
            #pragma unroll
            for (int k = 0; k < UNITS; ++k) a = fmaf(h1s[k], wh1[k], a);
            g1s[tid] = a;
        }
        __syncthreads();

        // ---- Phase B: layer-1 state update
        if (tid < UNITS) {
            float iv = sigmoidf_(g1s[tid]);
            float fv = sigmoidf_(g1s[UNITS + tid]);
            float gv = tanhf_  (g1s[2*UNITS + tid]);
            float ov = sigmoidf_(g1s[3*UNITS + tid]);
            c1 = gv * iv + fv * c1;
            h1s[tid] = ov * tanhf_(c1);
        }
        __syncthreads();

        // ---- Phase C: layer-2 gate pre-activations (input h1[t], recurrent h2[t-1])
        if (tid < GATES) {
            float a = b2r;
            #pragma unroll
            for (int k = 0; k < UNITS; ++k) a = fmaf(h1s[k], wx2[k], a);
            #pragma unroll
            for (int k = 0; k < UNITS; ++k) a = fmaf(h2s[k], wh2[k], a);
            g2s[tid] = a;
        }
        __syncthreads();

        // ---- Phase D: layer-2 state update + output head
        float p = 0.f;
        if (tid < UNITS) {
            float iv = sigmoidf_(g2s[tid]);
            float fv = sigmoidf_(g2s[UNITS + tid]);
            float gv = tanhf_  (g2s[2*UNITS + tid]);
            float ov = sigmoidf_(g2s[3*UNITS + tid]);
            c2 = gv * iv + fv * c2;
            float h2v = ov * tanhf_(c2);
            h2s[tid] = h2v;
            p = h2v * woutr;
        }
        // reduce p across lanes 0..31 of wave 0 (lanes 25..31 contribute 0)
        p += __shfl_down(p, 16, 32);
        p += __shfl_down(p, 8, 32);
        p += __shfl_down(p, 4, 32);
        p += __shfl_down(p, 2, 32);
        p += __shfl_down(p, 1, 32);
        if (tid == 0) out[(size_t)b * SEQ + t] = sigmoidf_(p + boutv);

        preval = prenext;
        // no barrier needed here: h2s(D,t) -> first read at C(t+1), separated by
        // barriers A(t+1),B(t+1); WAR on h2s separated by barrier C(t).
    }
}

// ---------------------------------------------------------------------------
extern "C" void kernel_launch(void* const* d_in, const int* in_sizes, int n_in,
                              void* d_out, int out_size, void* d_ws, size_t ws_size,
                              hipStream_t stream) {
    const float* x      = (const float*)d_in[0];
    const float* Wout   = (const float*)d_in[1];
    const float* bout   = (const float*)d_in[2];
    const float* l1_Wxi = (const float*)d_in[3];
    const float* l1_bi  = (const float*)d_in[4];
    const float* l1_Whi = (const float*)d_in[5];
    const float* l1_Wxf = (const float*)d_in[6];
    const float* l1_bf  = (const float*)d_in[7];
    const float* l1_Whf = (const float*)d_in[8];
    const float* l1_Wxc = (const float*)d_in[9];
    const float* l1_bc  = (const float*)d_in[10];
    const float* l1_Whc = (const float*)d_in[11];
    const float* l1_Wxo = (const float*)d_in[12];
    const float* l1_bo  = (const float*)d_in[13];
    const float* l1_Who = (const float*)d_in[14];
    const float* l2_Wxi = (const float*)d_in[15];
    const float* l2_bi  = (const float*)d_in[16];
    const float* l2_Whi = (const float*)d_in[17];
    const float* l2_Wxf = (const float*)d_in[18];
    const float* l2_bf  = (const float*)d_in[19];
    const float* l2_Whf = (const float*)d_in[20];
    const float* l2_Wxc = (const float*)d_in[21];
    const float* l2_bc  = (const float*)d_in[22];
    const float* l2_Whc = (const float*)d_in[23];
    const float* l2_Wxo = (const float*)d_in[24];
    const float* l2_bo  = (const float*)d_in[25];
    const float* l2_Who = (const float*)d_in[26];
    float* out = (float*)d_out;

    const size_t pre_bytes = (size_t)BATCH * SEQ * GATES * sizeof(float);

    if (ws_size >= pre_bytes) {
        float* pre = (float*)d_ws;
        // rows = BATCH*SEQ = 524288; 128 thread-slots per row; 256 threads/block
        const int rowsx = BATCH * SEQ;
        const int blocksA = (int)(((long long)rowsx * 128) / 256);
        proj1_kernel<<<blocksA, 256, 0, stream>>>(
            x, l1_Wxi, l1_bi, l1_Wxf, l1_bf, l1_Wxc, l1_bc, l1_Wxo, l1_bo, pre);
        lstm_seq_kernel<true><<<BATCH, 128, 0, stream>>>(
            x, pre,
            l1_Whi, l1_Whf, l1_Whc, l1_Who,
            l1_bi, l1_bf, l1_bc, l1_bo,
            l1_Wxi, l1_Wxf, l1_Wxc, l1_Wxo,
            l2_Wxi, l2_Wxf, l2_Wxc, l2_Wxo,
            l2_Whi, l2_Whf, l2_Whc, l2_Who,
            l2_bi, l2_bf, l2_bc, l2_bo,
            Wout, bout, out);
    } else {
        // ws too small: compute x-projection inline (slower but correct)
        lstm_seq_kernel<false><<<BATCH, 128, 0, stream>>>(
            x, nullptr,
            l1_Whi, l1_Whf, l1_Whc, l1_Who,
            l1_bi, l1_bf, l1_bc, l1_bo,
            l1_Wxi, l1_Wxf, l1_Wxc, l1_Wxo,
            l2_Wxi, l2_Wxf, l2_Wxc, l2_Wxo,
            l2_Whi, l2_Whf, l2_Whc, l2_Who,
            l2_bi, l2_bf, l2_bc, l2_bo,
            Wout, bout, out);
    }
}

// Round 2
// 2346.013 us; speedup vs baseline: 1.9655x; 1.9655x over previous
//
#include <hip/hip_runtime.h>
#include <cstdint>
#include <cstddef>

#define UNITS 25
#define GATES 100   // 4*25, gate order: i | f | c | o  (col = g*25+u)
#define IN_DIM 64
#define BATCH 256
#define SEQ 2048
#define BT (BATCH * SEQ)

#define R16(M) M(0) M(1) M(2) M(3) M(4) M(5) M(6) M(7) M(8) M(9) M(10) M(11) M(12) M(13) M(14) M(15)
#define R25(M) M(0) M(1) M(2) M(3) M(4) M(5) M(6) M(7) M(8) M(9) M(10) M(11) M(12) M(13) M(14) M(15) M(16) M(17) M(18) M(19) M(20) M(21) M(22) M(23) M(24)

__device__ __forceinline__ float sigmoidf_(float x) {
    return 1.0f / (1.0f + __expf(-x));
}
__device__ __forceinline__ float tanhf_(float x) {
    return 2.0f / (1.0f + __expf(-2.0f * x)) - 1.0f;
}

// quad broadcast: every lane gets the value held by lane (quad_base + J).
// v_mov_b32_dpp quad_perm(J,J,J,J) — VALU speed, no LDS pipe, no barrier.
template<int J>
__device__ __forceinline__ float qb(float v) {
    return __int_as_float(__builtin_amdgcn_mov_dpp(__float_as_int(v), (J) * 0x55, 0xF, 0xF, true));
}

// ---------------------------------------------------------------------------
// proj: pre2[col][row] = b[col] + x[row,:] @ Wx[:,col],  row = b*SEQ+t.
// lane = row: x row lives in 16 named float4 VGPRs; weight index is
// wave-uniform -> scalar (s_load) operands; stores coalesced (lane-contig).
// ---------------------------------------------------------------------------
__global__ __launch_bounds__(256)
void proj_kernel(const float* __restrict__ x,
                 const float* __restrict__ Wxi, const float* __restrict__ bi,
                 const float* __restrict__ Wxf, const float* __restrict__ bf,
                 const float* __restrict__ Wxc, const float* __restrict__ bc,
                 const float* __restrict__ Wxo, const float* __restrict__ bo,
                 float* __restrict__ pre2) {
    const int row = blockIdx.x * 256 + threadIdx.x;          // exact: 2048*256 = BT
    const float4* xp = (const float4*)(x + (size_t)row * IN_DIM);
    #define DX(q) const float4 X##q = xp[q];
    R16(DX)
    #undef DX
    #pragma unroll
    for (int g = 0; g < 4; ++g) {
        const float* W  = (g == 0) ? Wxi : (g == 1) ? Wxf : (g == 2) ? Wxc : Wxo;
        const float* bp = (g == 0) ? bi  : (g == 1) ? bf  : (g == 2) ? bc  : bo;
        #pragma unroll 1
        for (int u = 0; u < UNITS; ++u) {
            const float* wp = W + u;                          // wp[k*25] = W[k][u], uniform
            float acc = bp[u];
            #define PF(q) \
                acc = fmaf(X##q.x, wp[(4*(q)+0)*UNITS], acc); \
                acc = fmaf(X##q.y, wp[(4*(q)+1)*UNITS], acc); \
                acc = fmaf(X##q.z, wp[(4*(q)+2)*UNITS], acc); \
                acc = fmaf(X##q.w, wp[(4*(q)+3)*UNITS], acc);
            R16(PF)
            #undef PF
            pre2[(size_t)(g * UNITS + u) * BT + row] = acc;
        }
    }
}

// ---------------------------------------------------------------------------
// scan: one batch element per block, 128 threads (2 waves).
// lane = 4*u + g (u<25, g in {i,f,c,o}).  Per step:
//   AB: gate dot (pre + h1_old @ Wh1, weights in NAMED regs) -> activation
//       -> DPP quad exchange -> c1/h1 update in-lane (4x redundant per quad)
//   barrier1
//   CD: layer-2 dot (h1_new @ Wx2 + h2_old @ Wh2) -> same -> c2/h2
//       + head partial reduce via strided shfl_down
//   barrier2
// h1/h2 double-buffered in LDS => exactly 2 barriers/step, zero spills.
// ---------------------------------------------------------------------------
__global__ __launch_bounds__(128, 1)
void lstm_scan_kernel(const float* __restrict__ pre2,
                      const float* __restrict__ l1_Whi, const float* __restrict__ l1_Whf,
                      const float* __restrict__ l1_Whc, const float* __restrict__ l1_Who,
                      const float* __restrict__ l2_Wxi, const float* __restrict__ l2_Wxf,
                      const float* __restrict__ l2_Wxc, const float* __restrict__ l2_Wxo,
                      const float* __restrict__ l2_Whi, const float* __restrict__ l2_Whf,
                      const float* __restrict__ l2_Whc, const float* __restrict__ l2_Who,
                      const float* __restrict__ l2_bi,  const float* __restrict__ l2_bf,
                      const float* __restrict__ l2_bc,  const float* __restrict__ l2_bo,
                      const float* __restrict__ Wout,   const float* __restrict__ bout,
                      float* __restrict__ out) {
    const int tid = threadIdx.x;
    const int b   = blockIdx.x;
    const int u   = tid >> 2;
    const int g   = tid & 3;
    const bool gate = (tid < GATES);

    __shared__ alignas(16) float h1A[28], h1B[28], h2A[28], h2B[28];
    __shared__ float hq[2];

    if (tid < 28) { h1A[tid] = 0.f; h1B[tid] = 0.f; h2A[tid] = 0.f; h2B[tid] = 0.f; }

    // --- weights as named scalars (no allocas -> guaranteed VGPRs) ---
    #define DECLW(i) float wh1_##i = 0.f, wx2_##i = 0.f, wh2_##i = 0.f;
    R25(DECLW)
    #undef DECLW
    float b2r = 0.f, woutr = 0.f;
    float actA = 1.f, actB = -1.f, actC = 0.f;   // sigmoid; g==2 -> tanh via 2*sig(2a)-1
    float c1 = 0.f, c2 = 0.f;
    size_t pbase = 0;

    if (gate) {
        const float* Wh1 = (g==0)? l1_Whi : (g==1)? l1_Whf : (g==2)? l1_Whc : l1_Who;
        const float* Wx2 = (g==0)? l2_Wxi : (g==1)? l2_Wxf : (g==2)? l2_Wxc : l2_Wxo;
        const float* Wh2 = (g==0)? l2_Whi : (g==1)? l2_Whf : (g==2)? l2_Whc : l2_Who;
        const float* b2p = (g==0)? l2_bi  : (g==1)? l2_bf  : (g==2)? l2_bc  : l2_bo;
        #define LDW(i) wh1_##i = Wh1[(i)*UNITS + u]; \
                       wx2_##i = Wx2[(i)*UNITS + u]; \
                       wh2_##i = Wh2[(i)*UNITS + u];
        R25(LDW)
        #undef LDW
        b2r   = b2p[u];
        woutr = Wout[u];
        if (g == 2) { actA = 2.f; actB = -2.f; actC = -1.f; }
        pbase = (size_t)(g * UNITS + u) * BT + (size_t)b * SEQ;
    }
    const float boutv = bout[0];
    __syncthreads();

    auto step = [&](float preval, int t,
                    const float* h1c, float* h1n, const float* h2c, float* h2n) {
        // head for step t-1 (hq finalized at barrier2 of t-1; rewritten only
        // after barrier1 of step t) — runs on idle wave-1 lane.
        if (tid == 127 && t != 0)
            out[(size_t)b * SEQ + (t - 1)] = sigmoidf_(hq[0] + hq[1] + boutv);

        if (gate) {
            float a0 = preval, a1 = 0.f;
            #define F1(i) { const float hk = h1c[i]; \
                            if ((i) & 1) a1 = fmaf(hk, wh1_##i, a1); \
                            else         a0 = fmaf(hk, wh1_##i, a0); }
            R25(F1)
            #undef F1
            const float a  = a0 + a1;
            const float av = fmaf(actA, 1.f / (1.f + __expf(actB * a)), actC);
            const float iv = qb<0>(av), fv = qb<1>(av), gv = qb<2>(av), ov = qb<3>(av);
            c1 = fmaf(gv, iv, fv * c1);
            const float h1v = ov * tanhf_(c1);
            if (g == 0) h1n[u] = h1v;
        }
        __syncthreads();   // barrier1: h1_new visible

        float p = 0.f;
        if (gate) {
            float a0 = b2r, a1 = 0.f, d0 = 0.f, d1 = 0.f;
            #define F2(i) { const float hk = h1n[i]; const float qk = h2c[i]; \
                            if ((i) & 1) { a1 = fmaf(hk, wx2_##i, a1); d1 = fmaf(qk, wh2_##i, d1); } \
                            else         { a0 = fmaf(hk, wx2_##i, a0); d0 = fmaf(qk, wh2_##i, d0); } }
            R25(F2)
            #undef F2
            const float a  = (a0 + a1) + (d0 + d1);
            const float av = fmaf(actA, 1.f / (1.f + __expf(actB * a)), actC);
            const float iv = qb<0>(av), fv = qb<1>(av), gv = qb<2>(av), ov = qb<3>(av);
            c2 = fmaf(gv, iv, fv * c2);
            const float h2v = ov * tanhf_(c2);
            if (g == 0) { h2n[u] = h2v; p = h2v * woutr; }
        }
        // strided reduce: lane0 <- sum tids {0,4,..,60} (u0..15),
        //                 lane64 <- sum tids {64,68,..,124} (u16..24, rest 0)
        p += __shfl_down(p, 32);
        p += __shfl_down(p, 16);
        p += __shfl_down(p, 8);
        p += __shfl_down(p, 4);
        if (tid == 0)  hq[0] = p;
        if (tid == 64) hq[1] = p;
        __syncthreads();   // barrier2: h2_new + hq visible
    };

    float4 pc = make_float4(0.f, 0.f, 0.f, 0.f);
    if (gate) pc = *(const float4*)(pre2 + pbase);
    for (int t4 = 0; t4 < SEQ / 4; ++t4) {
        float4 pn = make_float4(0.f, 0.f, 0.f, 0.f);
        if (gate && (t4 + 1) < SEQ / 4)
            pn = *(const float4*)(pre2 + pbase + 4 * (t4 + 1));   // 4-step lead hides HBM
        const int t = 4 * t4;
        step(pc.x, t,     h1A, h1B, h2A, h2B);
        step(pc.y, t + 1, h1B, h1A, h2B, h2A);
        step(pc.z, t + 2, h1A, h1B, h2A, h2B);
        step(pc.w, t + 3, h1B, h1A, h2B, h2A);
        pc = pn;
    }
    if (tid == 127)
        out[(size_t)b * SEQ + (SEQ - 1)] = sigmoidf_(hq[0] + hq[1] + boutv);
}

// ---------------------------------------------------------------------------
extern "C" void kernel_launch(void* const* d_in, const int* in_sizes, int n_in,
                              void* d_out, int out_size, void* d_ws, size_t ws_size,
                              hipStream_t stream) {
    const float* x      = (const float*)d_in[0];
    const float* Wout   = (const float*)d_in[1];
    const float* bout   = (const float*)d_in[2];
    const float* l1_Wxi = (const float*)d_in[3];
    const float* l1_bi  = (const float*)d_in[4];
    const float* l1_Whi = (const float*)d_in[5];
    const float* l1_Wxf = (const float*)d_in[6];
    const float* l1_bf  = (const float*)d_in[7];
    const float* l1_Whf = (const float*)d_in[8];
    const float* l1_Wxc = (const float*)d_in[9];
    const float* l1_bc  = (const float*)d_in[10];
    const float* l1_Whc = (const float*)d_in[11];
    const float* l1_Wxo = (const float*)d_in[12];
    const float* l1_bo  = (const float*)d_in[13];
    const float* l1_Who = (const float*)d_in[14];
    const float* l2_Wxi = (const float*)d_in[15];
    const float* l2_bi  = (const float*)d_in[16];
    const float* l2_Whi = (const float*)d_in[17];
    const float* l2_Wxf = (const float*)d_in[18];
    const float* l2_bf  = (const float*)d_in[19];
    const float* l2_Whf = (const float*)d_in[20];
    const float* l2_Wxc = (const float*)d_in[21];
    const float* l2_bc  = (const float*)d_in[22];
    const float* l2_Whc = (const float*)d_in[23];
    const float* l2_Wxo = (const float*)d_in[24];
    const float* l2_bo  = (const float*)d_in[25];
    const float* l2_Who = (const float*)d_in[26];
    float* out = (float*)d_out;

    float* pre2 = (float*)d_ws;   // [100][BT], 210 MB — ws_size verified in R0

    proj_kernel<<<BT / 256, 256, 0, stream>>>(
        x, l1_Wxi, l1_bi, l1_Wxf, l1_bf, l1_Wxc, l1_bc, l1_Wxo, l1_bo, pre2);

    lstm_scan_kernel<<<BATCH, 128, 0, stream>>>(
        pre2,
        l1_Whi, l1_Whf, l1_Whc, l1_Who,
        l2_Wxi, l2_Wxf, l2_Wxc, l2_Wxo,
        l2_Whi, l2_Whf, l2_Whc, l2_Who,
        l2_bi, l2_bf, l2_bc, l2_bo,
        Wout, bout, out);
}

// Round 3
// 1608.802 us; speedup vs baseline: 2.8662x; 1.4582x over previous
//
#include <hip/hip_runtime.h>
#include <cstdint>
#include <cstddef>

#define UNITS 25
#define IN_DIM 64
#define BATCH 256
#define SEQ 2048
#define BT (BATCH * SEQ)
#define L2E 1.442695040888963f

#define R16(M) M(0) M(1) M(2) M(3) M(4) M(5) M(6) M(7) M(8) M(9) M(10) M(11) M(12) M(13) M(14) M(15)
#define R25(M) M(0) M(1) M(2) M(3) M(4) M(5) M(6) M(7) M(8) M(9) M(10) M(11) M(12) M(13) M(14) M(15) M(16) M(17) M(18) M(19) M(20) M(21) M(22) M(23) M(24)

// raw-hw transcendentals: v_exp_f32 (2^x) and v_rcp_f32 (~1ulp — fine vs 1.27e-2 threshold)
__device__ __forceinline__ float fsig(float x) {          // sigmoid
    return __builtin_amdgcn_rcpf(1.0f + __builtin_amdgcn_exp2f(-L2E * x));
}
__device__ __forceinline__ float ftanh(float x) {         // tanh = 2*sig(2x)-1
    return fmaf(2.0f, __builtin_amdgcn_rcpf(1.0f + __builtin_amdgcn_exp2f(-2.0f * L2E * x)), -1.0f);
}
// swap within lane pairs (0<->1, 2<->3, ...): v_mov_b32_dpp quad_perm(1,0,3,2)
__device__ __forceinline__ float dswap(float v) {
    return __int_as_float(__builtin_amdgcn_mov_dpp(__float_as_int(v), 0xB1, 0xF, 0xF, true));
}
// broadcast lane `lane`'s value to an SGPR (uniform float)
__device__ __forceinline__ float rdl(float v, int lane) {
    return __int_as_float(__builtin_amdgcn_readlane(__float_as_int(v), lane));
}
// force a uniform value into a VGPR (so FMAs can pair it with an SGPR operand)
__device__ __forceinline__ float to_vgpr(float s) {
    float d;
    asm("v_mov_b32 %0, %1" : "=v"(d) : "s"(s));
    return d;
}

// column order shared by prep/proj/scan: c<50: lane c of pass A (even=i, odd=f);
// c>=50: lane c-50 of pass B (even=c-gate, odd=o). u = l>>1.
__device__ __forceinline__ void colmap(int c, int& mg, int& u) {
    const int l = (c < 50) ? c : c - 50;
    u = l >> 1;
    mg = ((c < 50) ? 0 : 2) + (l & 1);
}

__device__ float g_Wt[100 * IN_DIM];   // [c][k] transposed layer-1 input weights
__device__ float g_bt[100];            // [c] layer-1 biases

// ---------------------------------------------------------------------------
__global__ void prep_kernel(const float* __restrict__ Wxi, const float* __restrict__ bi,
                            const float* __restrict__ Wxf, const float* __restrict__ bf,
                            const float* __restrict__ Wxc, const float* __restrict__ bc,
                            const float* __restrict__ Wxo, const float* __restrict__ bo) {
    const int c = threadIdx.x;
    if (c >= 100) return;
    int mg, u; colmap(c, mg, u);
    const float* W = (mg == 0) ? Wxi : (mg == 1) ? Wxf : (mg == 2) ? Wxc : Wxo;
    const float* b = (mg == 0) ? bi  : (mg == 1) ? bf  : (mg == 2) ? bc  : bo;
    for (int k = 0; k < IN_DIM; ++k) g_Wt[c * IN_DIM + k] = W[k * UNITS + u];
    g_bt[c] = b[u];
}

// ---------------------------------------------------------------------------
// proj: pre2[row][c] = g_bt[c] + x[row,:] @ g_Wt[c,:].  x row in 16 float4
// VGPRs; weights via uniform s_load_dwordx4; contiguous float4 stores.
// ---------------------------------------------------------------------------
__global__ __launch_bounds__(256)
void proj_kernel(const float* __restrict__ x, float* __restrict__ pre2) {
    const int row = blockIdx.x * 256 + threadIdx.x;    // grid exactly covers BT
    const float4* xp = (const float4*)(x + (size_t)row * IN_DIM);
    #define DX(q) const float4 X##q = xp[q];
    R16(DX)
    #undef DX
    float* orow = pre2 + (size_t)row * 100;
    #pragma unroll 1
    for (int j = 0; j < 25; ++j) {
        const int c0 = 4 * j;
        const float* wc0 = g_Wt + (size_t)c0 * IN_DIM;
        const float* wc1 = wc0 + IN_DIM;
        const float* wc2 = wc1 + IN_DIM;
        const float* wc3 = wc2 + IN_DIM;
        float a0 = g_bt[c0], a1 = g_bt[c0 + 1], a2 = g_bt[c0 + 2], a3 = g_bt[c0 + 3];
        #define PJ(q) { \
            const float4 w0 = ((const float4*)wc0)[q]; \
            const float4 w1 = ((const float4*)wc1)[q]; \
            const float4 w2 = ((const float4*)wc2)[q]; \
            const float4 w3 = ((const float4*)wc3)[q]; \
            a0 = fmaf(X##q.x, w0.x, a0); a0 = fmaf(X##q.y, w0.y, a0); \
            a0 = fmaf(X##q.z, w0.z, a0); a0 = fmaf(X##q.w, w0.w, a0); \
            a1 = fmaf(X##q.x, w1.x, a1); a1 = fmaf(X##q.y, w1.y, a1); \
            a1 = fmaf(X##q.z, w1.z, a1); a1 = fmaf(X##q.w, w1.w, a1); \
            a2 = fmaf(X##q.x, w2.x, a2); a2 = fmaf(X##q.y, w2.y, a2); \
            a2 = fmaf(X##q.z, w2.z, a2); a2 = fmaf(X##q.w, w2.w, a2); \
            a3 = fmaf(X##q.x, w3.x, a3); a3 = fmaf(X##q.y, w3.y, a3); \
            a3 = fmaf(X##q.z, w3.z, a3); a3 = fmaf(X##q.w, w3.w, a3); }
        R16(PJ)
        #undef PJ
        *(float4*)(orow + c0) = make_float4(a0, a1, a2, a3);
    }
}

// ---------------------------------------------------------------------------
// scan: 1 batch element per block, ONE wave of 64 lanes. No LDS, no barriers.
// Lane 2u handles gate cols (i,u) [pass A] and (c,u) [pass B]; lane 2u+1
// handles (f,u) and (o,u). Gate exchange = DPP pair swap; h broadcast =
// readlane -> SGPR; weights (150 floats) + Wout (25) live in V/AGPRs.
// ---------------------------------------------------------------------------
__global__ __launch_bounds__(64, 1)
void lstm_scan_kernel(const float* __restrict__ pre2,
                      const float* __restrict__ l1_Whi, const float* __restrict__ l1_Whf,
                      const float* __restrict__ l1_Whc, const float* __restrict__ l1_Who,
                      const float* __restrict__ l2_Wxi, const float* __restrict__ l2_Wxf,
                      const float* __restrict__ l2_Wxc, const float* __restrict__ l2_Wxo,
                      const float* __restrict__ l2_Whi, const float* __restrict__ l2_Whf,
                      const float* __restrict__ l2_Whc, const float* __restrict__ l2_Who,
                      const float* __restrict__ l2_bi,  const float* __restrict__ l2_bf,
                      const float* __restrict__ l2_bc,  const float* __restrict__ l2_bo,
                      const float* __restrict__ Wout,   const float* __restrict__ bout,
                      float* __restrict__ out) {
    const int tid = threadIdx.x;
    const int b   = blockIdx.x;
    const int lc  = (tid < 50) ? tid : 49;   // lanes 50..63 compute junk, never read
    const int uu  = lc >> 1;
    const int par = lc & 1;
    const bool odd = (tid & 1);              // == par for all real lanes

    // pass-B activation: even lane -> tanh (2*sig(2x)-1), odd lane -> sigmoid
    const float tA  = odd ? 1.0f : 2.0f;
    const float tC  = odd ? 0.0f : -1.0f;
    const float tSc = odd ? -L2E : -2.0f * L2E;

    const float* Wh1A = par ? l1_Whf : l1_Whi;
    const float* Wh1B = par ? l1_Who : l1_Whc;
    const float* Wx2A = par ? l2_Wxf : l2_Wxi;
    const float* Wx2B = par ? l2_Wxo : l2_Wxc;
    const float* Wh2A = par ? l2_Whf : l2_Whi;
    const float* Wh2B = par ? l2_Who : l2_Whc;
    const float b2A = par ? l2_bf[uu] : l2_bi[uu];
    const float b2B = par ? l2_bo[uu] : l2_bc[uu];

    #define DECLW(i) float wh1A_##i, wh1B_##i, wx2A_##i, wx2B_##i, wh2A_##i, wh2B_##i;
    R25(DECLW)
    #undef DECLW
    #define LDW(i) wh1A_##i = Wh1A[(i)*UNITS + uu]; wh1B_##i = Wh1B[(i)*UNITS + uu]; \
                   wx2A_##i = Wx2A[(i)*UNITS + uu]; wx2B_##i = Wx2B[(i)*UNITS + uu]; \
                   wh2A_##i = Wh2A[(i)*UNITS + uu]; wh2B_##i = Wh2B[(i)*UNITS + uu];
    R25(LDW)
    #undef LDW
    #define DWO(i) const float wo_##i = to_vgpr(Wout[i]);
    R25(DWO)
    #undef DWO
    const float boutv = bout[0];

    #define DECLH(i) float sh1_##i = 0.f, sh2_##i = 0.f;   // h broadcasts (SGPR-resident)
    R25(DECLH)
    #undef DECLH
    float c1 = 0.f, c2 = 0.f;

    const float* prow = pre2 + (size_t)b * SEQ * 100;

    auto step = [&](float pA, float pB, int oidx) {
        // ---- layer 1: a = pre + h1_old @ Wh1  (2 cols, 4 FMA chains)
        float aA0 = pA, aA1 = 0.f, aB0 = pB, aB1 = 0.f;
        #define F1(i) { if ((i) & 1) { aA1 = fmaf(sh1_##i, wh1A_##i, aA1); \
                                       aB1 = fmaf(sh1_##i, wh1B_##i, aB1); } \
                        else         { aA0 = fmaf(sh1_##i, wh1A_##i, aA0); \
                                       aB0 = fmaf(sh1_##i, wh1B_##i, aB0); } }
        R25(F1)
        #undef F1
        const float avA = fsig(aA0 + aA1);                                    // i or f
        const float avB = fmaf(tA, __builtin_amdgcn_rcpf(
                              1.0f + __builtin_amdgcn_exp2f(tSc * (aB0 + aB1))), tC); // c(tanh) or o
        const float pvA = dswap(avA), pvB = dswap(avB);
        const float iv = odd ? pvA : avA;
        const float fv = odd ? avA : pvA;
        const float gv = odd ? pvB : avB;
        const float ov = odd ? avB : pvB;
        c1 = fmaf(gv, iv, fv * c1);
        const float h1v = ov * ftanh(c1);
        #define BC1(i) sh1_##i = rdl(h1v, 2 * (i));
        R25(BC1)
        #undef BC1

        // ---- layer 2 dots: b2 + h1_new @ Wx2 + h2_old @ Wh2 (8 chains)
        float xA0 = b2A, xA1 = 0.f, xB0 = b2B, xB1 = 0.f;
        float hA0 = 0.f, hA1 = 0.f, hB0 = 0.f, hB1 = 0.f;
        #define F2(i) { if ((i) & 1) { xA1 = fmaf(sh1_##i, wx2A_##i, xA1); \
                                       xB1 = fmaf(sh1_##i, wx2B_##i, xB1); \
                                       hA1 = fmaf(sh2_##i, wh2A_##i, hA1); \
                                       hB1 = fmaf(sh2_##i, wh2B_##i, hB1); } \
                        else         { xA0 = fmaf(sh1_##i, wx2A_##i, xA0); \
                                       xB0 = fmaf(sh1_##i, wx2B_##i, xB0); \
                                       hA0 = fmaf(sh2_##i, wh2A_##i, hA0); \
                                       hB0 = fmaf(sh2_##i, wh2B_##i, hB0); } }
        R25(F2)
        #undef F2

        // ---- head for previous step (uses OLD sh2 = h2[t-1]; SGPR x VGPR FMAs)
        float hp0 = boutv, hp1 = 0.f;
        #define FH(i) { if ((i) & 1) hp1 = fmaf(sh2_##i, wo_##i, hp1); \
                        else         hp0 = fmaf(sh2_##i, wo_##i, hp0); }
        R25(FH)
        const float outv = fsig(hp0 + hp1);
        if (tid == 0) out[(size_t)b * SEQ + oidx] = outv;

        // ---- layer 2 state update
        const float dA = (xA0 + xA1) + (hA0 + hA1);
        const float dB = (xB0 + xB1) + (hB0 + hB1);
        const float avA2 = fsig(dA);
        const float avB2 = fmaf(tA, __builtin_amdgcn_rcpf(
                               1.0f + __builtin_amdgcn_exp2f(tSc * dB)), tC);
        const float pvA2 = dswap(avA2), pvB2 = dswap(avB2);
        const float iv2 = odd ? pvA2 : avA2;
        const float fv2 = odd ? avA2 : pvA2;
        const float gv2 = odd ? pvB2 : avB2;
        const float ov2 = odd ? avB2 : pvB2;
        c2 = fmaf(gv2, iv2, fv2 * c2);
        const float h2v = ov2 * ftanh(c2);
        #define BC2(i) sh2_##i = rdl(h2v, 2 * (i));
        R25(BC2)
        #undef BC2
    };

    // prime 4 steps (pre includes layer-1 bias; out[0] at t=0 is a dummy,
    // overwritten by the correct head at t=1)
    float pA0 = prow[lc],            pB0 = prow[50 + lc];
    float pA1 = prow[100 + lc],      pB1 = prow[150 + lc];
    float pA2 = prow[200 + lc],      pB2 = prow[250 + lc];
    float pA3 = prow[300 + lc],      pB3 = prow[350 + lc];

    #pragma unroll 1
    for (int t4 = 0; t4 < SEQ / 4; ++t4) {
        const int tn = (t4 < SEQ / 4 - 1) ? (t4 + 1) : (SEQ / 4 - 1);
        const float* nrow = prow + (size_t)tn * 400;     // prefetch next 4 steps
        const float nA0 = nrow[lc],        nB0 = nrow[50 + lc];
        const float nA1 = nrow[100 + lc],  nB1 = nrow[150 + lc];
        const float nA2 = nrow[200 + lc],  nB2 = nrow[250 + lc];
        const float nA3 = nrow[300 + lc],  nB3 = nrow[350 + lc];
        const int t = 4 * t4;
        step(pA0, pB0, (t == 0) ? 0 : t - 1);
        step(pA1, pB1, t);
        step(pA2, pB2, t + 1);
        step(pA3, pB3, t + 2);
        pA0 = nA0; pB0 = nB0; pA1 = nA1; pB1 = nB1;
        pA2 = nA2; pB2 = nB2; pA3 = nA3; pB3 = nB3;
    }
    // final head: sh2 now holds h2[SEQ-1]
    {
        float hp0 = boutv, hp1 = 0.f;
        R25(FH)
        if (tid == 0) out[(size_t)b * SEQ + (SEQ - 1)] = fsig(hp0 + hp1);
    }
    #undef FH
}

// ---------------------------------------------------------------------------
extern "C" void kernel_launch(void* const* d_in, const int* in_sizes, int n_in,
                              void* d_out, int out_size, void* d_ws, size_t ws_size,
                              hipStream_t stream) {
    const float* x      = (const float*)d_in[0];
    const float* Wout   = (const float*)d_in[1];
    const float* bout   = (const float*)d_in[2];
    const float* l1_Wxi = (const float*)d_in[3];
    const float* l1_bi  = (const float*)d_in[4];
    const float* l1_Whi = (const float*)d_in[5];
    const float* l1_Wxf = (const float*)d_in[6];
    const float* l1_bf  = (const float*)d_in[7];
    const float* l1_Whf = (const float*)d_in[8];
    const float* l1_Wxc = (const float*)d_in[9];
    const float* l1_bc  = (const float*)d_in[10];
    const float* l1_Whc = (const float*)d_in[11];
    const float* l1_Wxo = (const float*)d_in[12];
    const float* l1_bo  = (const float*)d_in[13];
    const float* l1_Who = (const float*)d_in[14];
    const float* l2_Wxi = (const float*)d_in[15];
    const float* l2_bi  = (const float*)d_in[16];
    const float* l2_Whi = (const float*)d_in[17];
    const float* l2_Wxf = (const float*)d_in[18];
    const float* l2_bf  = (const float*)d_in[19];
    const float* l2_Whf = (const float*)d_in[20];
    const float* l2_Wxc = (const float*)d_in[21];
    const float* l2_bc  = (const float*)d_in[22];
    const float* l2_Whc = (const float*)d_in[23];
    const float* l2_Wxo = (const float*)d_in[24];
    const float* l2_bo  = (const float*)d_in[25];
    const float* l2_Who = (const float*)d_in[26];
    float* out = (float*)d_out;

    float* pre2 = (float*)d_ws;   // [BT][100] = 210 MB (ws verified >= this in R0/R1)

    prep_kernel<<<1, 128, 0, stream>>>(l1_Wxi, l1_bi, l1_Wxf, l1_bf,
                                       l1_Wxc, l1_bc, l1_Wxo, l1_bo);
    proj_kernel<<<BT / 256, 256, 0, stream>>>(x, pre2);
    lstm_scan_kernel<<<BATCH, 64, 0, stream>>>(
        pre2,
        l1_Whi, l1_Whf, l1_Whc, l1_Who,
        l2_Wxi, l2_Wxf, l2_Wxc, l2_Wxo,
        l2_Whi, l2_Whf, l2_Whc, l2_Who,
        l2_bi, l2_bf, l2_bc, l2_bo,
        Wout, bout, out);
}

// Round 4
// 1124.967 us; speedup vs baseline: 4.0989x; 1.4301x over previous
//
#include <hip/hip_runtime.h>
#include <cstdint>
#include <cstddef>

#define UNITS 25
#define IN_DIM 64
#define BATCH 256
#define SEQ 2048
#define BT (BATCH * SEQ)
#define L2E 1.442695040888963f

typedef _Float16 h2t __attribute__((ext_vector_type(2)));

#define R13(M) M(0) M(1) M(2) M(3) M(4) M(5) M(6) M(7) M(8) M(9) M(10) M(11) M(12)
#define R16(M) M(0) M(1) M(2) M(3) M(4) M(5) M(6) M(7) M(8) M(9) M(10) M(11) M(12) M(13) M(14) M(15)

// f32 pair -> packed f16 (v_cvt_pkrtz_f16_f32, 1 inst)
__device__ __forceinline__ unsigned pk16(float lo, float hi) {
    return __builtin_bit_cast(unsigned, __builtin_amdgcn_cvt_pkrtz(lo, hi));
}
// 2-way f16 dot with f32 accumulate (v_dot2_f32_f16)
__device__ __forceinline__ float fdot2_(unsigned w, unsigned h, float c) {
#if __has_builtin(__builtin_amdgcn_fdot2)
    return __builtin_amdgcn_fdot2(__builtin_bit_cast(h2t, w),
                                  __builtin_bit_cast(h2t, h), c, false);
#else
    h2t W = __builtin_bit_cast(h2t, w), H = __builtin_bit_cast(h2t, h);
    return fmaf((float)W.x, (float)H.x, fmaf((float)W.y, (float)H.y, c));
#endif
}
// swap within lane pairs (0<->1,...): quad_perm(1,0,3,2)
__device__ __forceinline__ float dswap(float v) {
    return __int_as_float(__builtin_amdgcn_mov_dpp(__float_as_int(v), 0xB1, 0xF, 0xF, true));
}
// every lane gets quad-position-2's value: quad_perm(2,2,2,2) -> lane 4q sees lane 4q+2
__device__ __forceinline__ float dpp2(float v) {
    return __int_as_float(__builtin_amdgcn_mov_dpp(__float_as_int(v), 0xAA, 0xF, 0xF, true));
}
__device__ __forceinline__ unsigned rdlu(unsigned v, int lane) {
    return (unsigned)__builtin_amdgcn_readlane((int)v, lane);
}
__device__ __forceinline__ float sig_raw(float a) {      // sigma from pre-scaled acc
    return __builtin_amdgcn_rcpf(1.0f + __builtin_amdgcn_exp2f(a));
}
__device__ __forceinline__ float tanh5(float c) {        // tanh(c), c unscaled
    return fmaf(2.0f, __builtin_amdgcn_rcpf(
        1.0f + __builtin_amdgcn_exp2f(-2.0f * L2E * c)), -1.0f);
}

// Column order (shared prep/proj/scan): c<50 = pass A (even=i, odd=f);
// c>=50 = pass B (even=c-gate[tanh], odd=o). unit u = ((c%50)>>1).
// Per-column scale folded into weights/biases: tanh cols -2*L2E, sigmoid cols -L2E.

__device__ unsigned g_w1[13 * 100];   // layer-1 recurrent, f16 pairs over k, scaled
__device__ unsigned g_wx[13 * 100];   // layer-2 input (h1) weights
__device__ unsigned g_wh[13 * 100];   // layer-2 recurrent
__device__ unsigned g_wo[13];         // head weights, f16 pairs, unscaled
__device__ float    g_Wp[50 * 64 * 2]; // proj weights: [(j*64+k)*2+p], scaled f32
__device__ float    g_bp[100];         // proj bias pairs [j*2+p], scaled

// ---------------------------------------------------------------------------
__global__ void prep_kernel(const float* __restrict__ l1_Whi, const float* __restrict__ l1_Whf,
                            const float* __restrict__ l1_Whc, const float* __restrict__ l1_Who,
                            const float* __restrict__ l1_Wxi, const float* __restrict__ l1_Wxf,
                            const float* __restrict__ l1_Wxc, const float* __restrict__ l1_Wxo,
                            const float* __restrict__ l1_bi,  const float* __restrict__ l1_bf,
                            const float* __restrict__ l1_bc,  const float* __restrict__ l1_bo,
                            const float* __restrict__ l2_Wxi, const float* __restrict__ l2_Wxf,
                            const float* __restrict__ l2_Wxc, const float* __restrict__ l2_Wxo,
                            const float* __restrict__ l2_Whi, const float* __restrict__ l2_Whf,
                            const float* __restrict__ l2_Whc, const float* __restrict__ l2_Who,
                            const float* __restrict__ Wout) {
    const int c = threadIdx.x;
    if (c < 100) {
        const int half = (c >= 50);
        const int l = half ? c - 50 : c;
        const int u = l >> 1;
        const int par = l & 1;
        const float s = (half && !par) ? (-2.0f * L2E) : (-L2E);
        const float* W1 = half ? (par ? l1_Who : l1_Whc) : (par ? l1_Whf : l1_Whi);
        const float* WX = half ? (par ? l2_Wxo : l2_Wxc) : (par ? l2_Wxf : l2_Wxi);
        const float* WH = half ? (par ? l2_Who : l2_Whc) : (par ? l2_Whf : l2_Whi);
        const float* WI = half ? (par ? l1_Wxo : l1_Wxc) : (par ? l1_Wxf : l1_Wxi);
        const float* bI = half ? (par ? l1_bo  : l1_bc)  : (par ? l1_bf  : l1_bi);
        for (int i = 0; i < 13; ++i) {
            const int k0 = 2 * i, k1 = 2 * i + 1;
            const float a1 = s * W1[k0 * UNITS + u];
            const float b1 = (k1 < UNITS) ? s * W1[k1 * UNITS + u] : 0.f;
            g_w1[i * 100 + c] = pk16(a1, b1);
            const float ax = s * WX[k0 * UNITS + u];
            const float bx = (k1 < UNITS) ? s * WX[k1 * UNITS + u] : 0.f;
            g_wx[i * 100 + c] = pk16(ax, bx);
            const float ah = s * WH[k0 * UNITS + u];
            const float bh = (k1 < UNITS) ? s * WH[k1 * UNITS + u] : 0.f;
            g_wh[i * 100 + c] = pk16(ah, bh);
        }
        const int j = c >> 1, p = c & 1;
        for (int k = 0; k < IN_DIM; ++k)
            g_Wp[(j * IN_DIM + k) * 2 + p] = s * WI[k * UNITS + u];
        g_bp[j * 2 + p] = s * bI[u];
    }
    if (c == 100) {
        for (int i = 0; i < 13; ++i) {
            const int k1 = 2 * i + 1;
            g_wo[i] = pk16(Wout[2 * i], (k1 < UNITS) ? Wout[k1] : 0.f);
        }
    }
}

// ---------------------------------------------------------------------------
// proj: pre2[row][c] = s_c*(b_c + x[row,:]@Wx[:,c]).  Weights staged in LDS
// (guaranteed hits, broadcast reads on the LDS pipe); x row in 16 float4 regs.
// ---------------------------------------------------------------------------
__global__ __launch_bounds__(256)
void proj_kernel(const float* __restrict__ x, float* __restrict__ pre2) {
    __shared__ float wls[50 * 64 * 2];
    __shared__ float bls[100];
    for (int i = threadIdx.x; i < 6400; i += 256) wls[i] = g_Wp[i];
    if (threadIdx.x < 100) bls[threadIdx.x] = g_bp[threadIdx.x];
    __syncthreads();

    const int row = blockIdx.x * 256 + threadIdx.x;   // grid exactly covers BT
    const float4* xp = (const float4*)(x + (size_t)row * IN_DIM);
    #define DX(q) const float4 X##q = xp[q];
    R16(DX)
    #undef DX
    float* orow = pre2 + (size_t)row * 100;
    #pragma unroll 2
    for (int j = 0; j < 50; ++j) {
        const float4* wj = (const float4*)(wls + j * 128);
        float aL = bls[2 * j], aH = bls[2 * j + 1];
        #define PJ(q) { \
            const float4 wa = wj[2 * (q)]; \
            const float4 wb = wj[2 * (q) + 1]; \
            aL = fmaf(X##q.x, wa.x, aL); aH = fmaf(X##q.x, wa.y, aH); \
            aL = fmaf(X##q.y, wa.z, aL); aH = fmaf(X##q.y, wa.w, aH); \
            aL = fmaf(X##q.z, wb.x, aL); aH = fmaf(X##q.z, wb.y, aH); \
            aL = fmaf(X##q.w, wb.z, aL); aH = fmaf(X##q.w, wb.w, aH); }
        R16(PJ)
        #undef PJ
        *(float2*)(orow + 2 * j) = make_float2(aL, aH);
    }
}

// ---------------------------------------------------------------------------
// scan: 1 batch element per block, ONE wave. No LDS/barriers. Per step ~155
// inst: 78 dot2 (f16 pairs), 26 readlane (pair-packed h), scaled-exp acts.
// F1 dot of step t+1 interleaved with F2 dots of step t (shared h1 broadcast).
// ---------------------------------------------------------------------------
template<bool HOFF>
__global__ __launch_bounds__(64, 1)
void lstm_scan_kernel(const float* __restrict__ pre2,
                      const float* __restrict__ l2_bi, const float* __restrict__ l2_bf,
                      const float* __restrict__ l2_bc, const float* __restrict__ l2_bo,
                      const float* __restrict__ bout,
                      float* __restrict__ h2buf, float* __restrict__ out) {
    const int tid = threadIdx.x;
    const int b   = blockIdx.x;
    const int lc  = (tid < 50) ? tid : 49;   // lanes 50..63 compute junk, never read
    const int uu  = lc >> 1;
    const bool odd = (tid & 1);

    // pass-B activation per parity: even lane -> tanh form, odd -> sigmoid
    const float tA = odd ? 1.0f : 2.0f;
    const float tC = odd ? 0.0f : -1.0f;

    // layer-2 biases, pre-scaled like their columns
    const float b2A = (odd ? l2_bf[uu] : l2_bi[uu]) * (-L2E);
    const float b2B = odd ? (l2_bo[uu] * (-L2E)) : (l2_bc[uu] * (-2.0f * L2E));
    const float boutv = bout[0];

    // weights: f16 pairs in VGPRs (78 u32)
    #define LW(i) const unsigned w1A_##i = g_w1[(i)*100 + lc],      \
                                 w1B_##i = g_w1[(i)*100 + 50 + lc], \
                                 wxA_##i = g_wx[(i)*100 + lc],      \
                                 wxB_##i = g_wx[(i)*100 + 50 + lc], \
                                 whA_##i = g_wh[(i)*100 + lc],      \
                                 whB_##i = g_wh[(i)*100 + 50 + lc];
    R13(LW)
    #undef LW
    #define LWO(i) const unsigned wo_##i = HOFF ? 0u : g_wo[i];
    R13(LWO)
    #undef LWO

    // h broadcasts: packed f16 unit-pairs in SGPRs
    #define DH(i) unsigned s1_##i = 0u, s2_##i = 0u;
    R13(DH)
    #undef DH
    float c1 = 0.f, c2 = 0.f;

    const float* pp = pre2 + (size_t)b * SEQ * 100 + lc;   // per-lane column ptr
    float* h2p = HOFF ? (h2buf + (size_t)b * SEQ * UNITS + uu) : nullptr;
    const bool st = (tid < 50) && !odd;

    // prime: F1 acc for t=0 is just pre(0) (h1(-1)=0)
    float aA = pp[0], aB = pp[50];
    float pA1 = pp[100], pB1 = pp[150];
    float pA2 = pp[200], pB2 = pp[250];
    float pA3 = pp[300], pB3 = pp[350];

    auto step = [&](float pnA, float pnB, int t) {
        // ---- layer-1 activations from carried dot (aA,aB pre-scaled)
        const float avA = sig_raw(aA);                        // i (even) / f (odd)
        const float avB = fmaf(tA, sig_raw(aB), tC);          // g / o
        const float fv = dswap(avA);
        const float ov = dswap(avB);
        c1 = fmaf(avB, avA, fv * c1);                         // even lanes valid
        const float h1v = ov * tanh5(c1);
        // ---- pack + broadcast h1 (lane 4q: pair(h_2q, h_2q+1))
        const unsigned m1 = pk16(h1v, dpp2(h1v));
        #define BC1(i) s1_##i = rdlu(m1, 4 * (i));
        R13(BC1)
        #undef BC1
        // ---- interleaved dots: F2(t) + F1(t+1)
        float naA = pnA, naB = pnB;
        float xA = b2A, xB = b2B, hA = 0.f, hB = 0.f;
        #define DD(i) xA  = fdot2_(wxA_##i, s1_##i, xA);  \
                      xB  = fdot2_(wxB_##i, s1_##i, xB);  \
                      hA  = fdot2_(whA_##i, s2_##i, hA);  \
                      hB  = fdot2_(whB_##i, s2_##i, hB);  \
                      naA = fdot2_(w1A_##i, s1_##i, naA); \
                      naB = fdot2_(w1B_##i, s1_##i, naB);
        R13(DD)
        #undef DD
        // ---- layer-2 activations + state
        const float avA2 = sig_raw(xA + hA);
        const float avB2 = fmaf(tA, sig_raw(xB + hB), tC);
        const float fv2 = dswap(avA2);
        const float ov2 = dswap(avB2);
        c2 = fmaf(avB2, avA2, fv2 * c2);
        const float h2v = ov2 * tanh5(c2);
        if (HOFF) {
            if (st) h2p[(size_t)t * UNITS] = h2v;
        }
        const unsigned m2 = pk16(h2v, dpp2(h2v));
        #define BC2(i) s2_##i = rdlu(m2, 4 * (i));
        R13(BC2)
        #undef BC2
        if (!HOFF) {
            float hp = boutv;
            #define HH(i) hp = fdot2_(wo_##i, s2_##i, hp);
            R13(HH)
            #undef HH
            if (tid == 0) out[(size_t)b * SEQ + t] = sig_raw(-L2E * hp);
        }
        aA = naA; aB = naB;
    };

    #pragma unroll 1
    for (int g = 0; g < SEQ / 4; ++g) {
        const int gn = (g < SEQ / 4 - 1) ? g + 1 : g;
        const float* pg = pp + (size_t)gn * 400;    // prefetch next 4 rows
        const float nA0 = pg[0],   nB0 = pg[50];
        const float nA1 = pg[100], nB1 = pg[150];
        const float nA2 = pg[200], nB2 = pg[250];
        const float nA3 = pg[300], nB3 = pg[350];
        const int t = 4 * g;
        step(pA1, pB1, t);        // consumes pre(t+1)
        step(pA2, pB2, t + 1);
        step(pA3, pB3, t + 2);
        step(nA0, nB0, t + 3);    // pre(t+4)
        pA1 = nA1; pB1 = nB1;
        pA2 = nA2; pB2 = nB2;
        pA3 = nA3; pB3 = nB3;
    }
}

// ---------------------------------------------------------------------------
// head: out[r] = sigmoid(h2[r,:] @ Wout + bout), trivially parallel
// ---------------------------------------------------------------------------
__global__ __launch_bounds__(256)
void head_kernel(const float* __restrict__ h2buf, const float* __restrict__ Wout,
                 const float* __restrict__ bout, float* __restrict__ out) {
    __shared__ float wl[26];
    if (threadIdx.x < 25) wl[threadIdx.x] = Wout[threadIdx.x];
    if (threadIdx.x == 25) wl[25] = bout[0];
    __syncthreads();
    const int r = blockIdx.x * 256 + threadIdx.x;     // grid exactly covers BT
    const float* hp = h2buf + (size_t)r * UNITS;
    float p0 = wl[25], p1 = 0.f;
    #pragma unroll
    for (int k = 0; k < UNITS; ++k) {
        if (k & 1) p1 = fmaf(hp[k], wl[k], p1);
        else       p0 = fmaf(hp[k], wl[k], p0);
    }
    out[r] = sig_raw(-L2E * (p0 + p1));
}

// ---------------------------------------------------------------------------
extern "C" void kernel_launch(void* const* d_in, const int* in_sizes, int n_in,
                              void* d_out, int out_size, void* d_ws, size_t ws_size,
                              hipStream_t stream) {
    const float* x      = (const float*)d_in[0];
    const float* Wout   = (const float*)d_in[1];
    const float* bout   = (const float*)d_in[2];
    const float* l1_Wxi = (const float*)d_in[3];
    const float* l1_bi  = (const float*)d_in[4];
    const float* l1_Whi = (const float*)d_in[5];
    const float* l1_Wxf = (const float*)d_in[6];
    const float* l1_bf  = (const float*)d_in[7];
    const float* l1_Whf = (const float*)d_in[8];
    const float* l1_Wxc = (const float*)d_in[9];
    const float* l1_bc  = (const float*)d_in[10];
    const float* l1_Whc = (const float*)d_in[11];
    const float* l1_Wxo = (const float*)d_in[12];
    const float* l1_bo  = (const float*)d_in[13];
    const float* l1_Who = (const float*)d_in[14];
    const float* l2_Wxi = (const float*)d_in[15];
    const float* l2_bi  = (const float*)d_in[16];
    const float* l2_Whi = (const float*)d_in[17];
    const float* l2_Wxf = (const float*)d_in[18];
    const float* l2_bf  = (const float*)d_in[19];
    const float* l2_Whf = (const float*)d_in[20];
    const float* l2_Wxc = (const float*)d_in[21];
    const float* l2_bc  = (const float*)d_in[22];
    const float* l2_Whc = (const float*)d_in[23];
    const float* l2_Wxo = (const float*)d_in[24];
    const float* l2_bo  = (const float*)d_in[25];
    const float* l2_Who = (const float*)d_in[26];
    float* out = (float*)d_out;

    const size_t pre_bytes = (size_t)BT * 100 * sizeof(float);   // 210 MB
    const size_t h2_bytes  = (size_t)BT * UNITS * sizeof(float); // 52.4 MB
    float* pre2 = (float*)d_ws;

    prep_kernel<<<1, 128, 0, stream>>>(
        l1_Whi, l1_Whf, l1_Whc, l1_Who,
        l1_Wxi, l1_Wxf, l1_Wxc, l1_Wxo,
        l1_bi, l1_bf, l1_bc, l1_bo,
        l2_Wxi, l2_Wxf, l2_Wxc, l2_Wxo,
        l2_Whi, l2_Whf, l2_Whc, l2_Who,
        Wout);
    proj_kernel<<<BT / 256, 256, 0, stream>>>(x, pre2);

    if (ws_size >= pre_bytes + h2_bytes) {
        float* h2buf = (float*)((char*)d_ws + pre_bytes);
        lstm_scan_kernel<true><<<BATCH, 64, 0, stream>>>(
            pre2, l2_bi, l2_bf, l2_bc, l2_bo, bout, h2buf, out);
        head_kernel<<<BT / 256, 256, 0, stream>>>(h2buf, Wout, bout, out);
    } else {
        lstm_scan_kernel<false><<<BATCH, 64, 0, stream>>>(
            pre2, l2_bi, l2_bf, l2_bc, l2_bo, bout, nullptr, out);
    }
}

// Round 5
// 1117.353 us; speedup vs baseline: 4.1269x; 1.0068x over previous
//
#include <hip/hip_runtime.h>
#include <cstdint>
#include <cstddef>

#define UNITS 25
#define IN_DIM 64
#define BATCH 256
#define SEQ 2048
#define BT (BATCH * SEQ)
#define L2E 1.442695040888963f

typedef _Float16 h2t __attribute__((ext_vector_type(2)));

#define R13(M) M(0) M(1) M(2) M(3) M(4) M(5) M(6) M(7) M(8) M(9) M(10) M(11) M(12)

// f32 pair -> packed f16 (v_cvt_pkrtz_f16_f32)
__device__ __forceinline__ unsigned pk16(float lo, float hi) {
    return __builtin_bit_cast(unsigned, __builtin_amdgcn_cvt_pkrtz(lo, hi));
}
__device__ __forceinline__ float lo16(unsigned u) {
    return (float)__builtin_bit_cast(h2t, u).x;
}
__device__ __forceinline__ float hi16(unsigned u) {
    return (float)__builtin_bit_cast(h2t, u).y;
}
// 2-way f16 dot with f32 accumulate (v_dot2_f32_f16)
__device__ __forceinline__ float fdot2_(unsigned w, unsigned h, float c) {
#if __has_builtin(__builtin_amdgcn_fdot2)
    return __builtin_amdgcn_fdot2(__builtin_bit_cast(h2t, w),
                                  __builtin_bit_cast(h2t, h), c, false);
#else
    h2t W = __builtin_bit_cast(h2t, w), H = __builtin_bit_cast(h2t, h);
    return fmaf((float)W.x, (float)H.x, fmaf((float)W.y, (float)H.y, c));
#endif
}
// swap within lane pairs (0<->1,...): quad_perm(1,0,3,2)
__device__ __forceinline__ float dswap(float v) {
    return __int_as_float(__builtin_amdgcn_mov_dpp(__float_as_int(v), 0xB1, 0xF, 0xF, true));
}
// lane 4q+p gets lane 4q+2's value: quad_perm(2,2,2,2)
__device__ __forceinline__ float dpp2(float v) {
    return __int_as_float(__builtin_amdgcn_mov_dpp(__float_as_int(v), 0xAA, 0xF, 0xF, true));
}
__device__ __forceinline__ unsigned rdlu(unsigned v, int lane) {
    return (unsigned)__builtin_amdgcn_readlane((int)v, lane);
}
__device__ __forceinline__ float sig_raw(float a) {      // sigma from pre-scaled acc
    return __builtin_amdgcn_rcpf(1.0f + __builtin_amdgcn_exp2f(a));
}
__device__ __forceinline__ float tanh5(float c) {        // tanh(c), c unscaled
    return fmaf(2.0f, __builtin_amdgcn_rcpf(
        1.0f + __builtin_amdgcn_exp2f(-2.0f * L2E * c)), -1.0f);
}
// pinned global load: volatile asm result cannot be rematerialized by the
// compiler -> the value MUST stay resident in a VGPR (fix for R3's VGPR=56
// remat-every-step pathology).
__device__ __forceinline__ unsigned ldpin(const unsigned* p) {
    unsigned v;
    asm volatile("global_load_dword %0, %1, off\n\ts_waitcnt vmcnt(0)"
                 : "=v"(v) : "v"(p) : "memory");
    return v;
}

// Column order (shared prep/proj/scan): c<50 = pass A (even=i, odd=f);
// c>=50 = pass B (even=c-gate[tanh], odd=o). unit u = ((c%50)>>1).
// Activation scale folded into weights/biases: tanh cols -2*L2E, else -L2E.

__device__ unsigned g_w1[13 * 100];    // layer-1 recurrent, f16 k-pairs, scaled
__device__ unsigned g_wx[13 * 100];    // layer-2 input (h1) weights
__device__ unsigned g_wh[13 * 100];    // layer-2 recurrent
__device__ unsigned g_wo[13];          // head weights, f16 pairs, unscaled
__device__ unsigned g_Wp16[100 * 32];  // proj weights: [c][kpair] f16 pairs, scaled
__device__ float    g_bp[100];         // proj bias [c], scaled

// ---------------------------------------------------------------------------
__global__ void prep_kernel(const float* __restrict__ l1_Whi, const float* __restrict__ l1_Whf,
                            const float* __restrict__ l1_Whc, const float* __restrict__ l1_Who,
                            const float* __restrict__ l1_Wxi, const float* __restrict__ l1_Wxf,
                            const float* __restrict__ l1_Wxc, const float* __restrict__ l1_Wxo,
                            const float* __restrict__ l1_bi,  const float* __restrict__ l1_bf,
                            const float* __restrict__ l1_bc,  const float* __restrict__ l1_bo,
                            const float* __restrict__ l2_Wxi, const float* __restrict__ l2_Wxf,
                            const float* __restrict__ l2_Wxc, const float* __restrict__ l2_Wxo,
                            const float* __restrict__ l2_Whi, const float* __restrict__ l2_Whf,
                            const float* __restrict__ l2_Whc, const float* __restrict__ l2_Who,
                            const float* __restrict__ Wout) {
    const int c = threadIdx.x;
    if (c < 100) {
        const int half = (c >= 50);
        const int l = half ? c - 50 : c;
        const int u = l >> 1;
        const int par = l & 1;
        const float s = (half && !par) ? (-2.0f * L2E) : (-L2E);
        const float* W1 = half ? (par ? l1_Who : l1_Whc) : (par ? l1_Whf : l1_Whi);
        const float* WX = half ? (par ? l2_Wxo : l2_Wxc) : (par ? l2_Wxf : l2_Wxi);
        const float* WH = half ? (par ? l2_Who : l2_Whc) : (par ? l2_Whf : l2_Whi);
        const float* WI = half ? (par ? l1_Wxo : l1_Wxc) : (par ? l1_Wxf : l1_Wxi);
        const float* bI = half ? (par ? l1_bo  : l1_bc)  : (par ? l1_bf  : l1_bi);
        for (int i = 0; i < 13; ++i) {
            const int k0 = 2 * i, k1 = 2 * i + 1;
            const float a1 = s * W1[k0 * UNITS + u];
            const float b1 = (k1 < UNITS) ? s * W1[k1 * UNITS + u] : 0.f;
            g_w1[i * 100 + c] = pk16(a1, b1);
            const float ax = s * WX[k0 * UNITS + u];
            const float bx = (k1 < UNITS) ? s * WX[k1 * UNITS + u] : 0.f;
            g_wx[i * 100 + c] = pk16(ax, bx);
            const float ah = s * WH[k0 * UNITS + u];
            const float bh = (k1 < UNITS) ? s * WH[k1 * UNITS + u] : 0.f;
            g_wh[i * 100 + c] = pk16(ah, bh);
        }
        for (int kp = 0; kp < 32; ++kp)
            g_Wp16[c * 32 + kp] = pk16(s * WI[(2 * kp) * UNITS + u],
                                       s * WI[(2 * kp + 1) * UNITS + u]);
        g_bp[c] = s * bI[u];
    }
    if (c == 100) {
        for (int i = 0; i < 13; ++i) {
            const int k1 = 2 * i + 1;
            g_wo[i] = pk16(Wout[2 * i], (k1 < UNITS) ? Wout[k1] : 0.f);
        }
    }
}

// ---------------------------------------------------------------------------
// proj: pre2h[row][c] = pk16(scaled pre of col c, col c+50).  2 rows/thread
// (halves LDS traffic), dot2 f16 math (halves VALU), f16-pair output (halves
// HBM write: 105 MB). Weights: f16-pair uint4 in LDS, broadcast reads.
// ---------------------------------------------------------------------------
__global__ __launch_bounds__(256, 2)
void proj_kernel(const float* __restrict__ x, unsigned* __restrict__ pre2h) {
    __shared__ unsigned wls[100 * 32];
    __shared__ float bls[100];
    for (int i = threadIdx.x; i < 3200; i += 256) wls[i] = g_Wp16[i];
    if (threadIdx.x < 100) bls[threadIdx.x] = g_bp[threadIdx.x];
    __syncthreads();

    const int r0 = blockIdx.x * 512 + threadIdx.x;   // 1024 blocks cover BT
    const int r1 = r0 + 256;

    uint4 xp[2][8];                                  // x rows as f16 k-pairs
    #pragma unroll
    for (int r = 0; r < 2; ++r) {
        const float4* xr = (const float4*)(x + (size_t)(r ? r1 : r0) * IN_DIM);
        #pragma unroll
        for (int j = 0; j < 8; ++j) {
            const float4 a = xr[2 * j], b = xr[2 * j + 1];
            xp[r][j] = make_uint4(pk16(a.x, a.y), pk16(a.z, a.w),
                                  pk16(b.x, b.y), pk16(b.z, b.w));
        }
    }
    unsigned* o0 = pre2h + (size_t)r0 * 50;
    unsigned* o1 = pre2h + (size_t)r1 * 50;

    #pragma unroll 1
    for (int c = 0; c < 50; ++c) {
        const uint4* wA = (const uint4*)(wls + c * 32);          // col c
        const uint4* wB = (const uint4*)(wls + (c + 50) * 32);   // col c+50
        float aA0 = bls[c],      aA1 = bls[c + 256 - 256 + 50] * 0.f; // see init below
        aA1 = 0.f;
        float bA0 = 0.f, bA1 = 0.f;
        float aB0 = bls[c + 50], aB1 = 0.f, bB0 = 0.f, bB1 = 0.f;
        float cA0 = bls[c],      cA1 = 0.f, dA0 = 0.f, dA1 = 0.f; // row1 chains
        float cB0 = bls[c + 50], cB1 = 0.f, dB0 = 0.f, dB1 = 0.f;
        #pragma unroll
        for (int j = 0; j < 8; ++j) {
            const uint4 wa = wA[j], wb = wB[j];
            const uint4 x0 = xp[0][j], x1 = xp[1][j];
            aA0 = fdot2_(wa.x, x0.x, aA0); bA0 = fdot2_(wa.y, x0.y, bA0);
            aA1 = fdot2_(wa.z, x0.z, aA1); bA1 = fdot2_(wa.w, x0.w, bA1);
            aB0 = fdot2_(wb.x, x0.x, aB0); bB0 = fdot2_(wb.y, x0.y, bB0);
            aB1 = fdot2_(wb.z, x0.z, aB1); bB1 = fdot2_(wb.w, x0.w, bB1);
            cA0 = fdot2_(wa.x, x1.x, cA0); dA0 = fdot2_(wa.y, x1.y, dA0);
            cA1 = fdot2_(wa.z, x1.z, cA1); dA1 = fdot2_(wa.w, x1.w, dA1);
            cB0 = fdot2_(wb.x, x1.x, cB0); dB0 = fdot2_(wb.y, x1.y, dB0);
            cB1 = fdot2_(wb.z, x1.z, cB1); dB1 = fdot2_(wb.w, x1.w, dB1);
        }
        o0[c] = pk16((aA0 + aA1) + (bA0 + bA1), (aB0 + aB1) + (bB0 + bB1));
        o1[c] = pk16((cA0 + cA1) + (dA0 + dA1), (cB0 + cB1) + (dB0 + dB1));
    }
}

// ---------------------------------------------------------------------------
// scan: 1 batch element per block, ONE wave, no LDS/barriers. Weights pinned
// in VGPRs via volatile-asm loads; waves_per_eu(1,1) -> 512-VGPR budget.
// pre read as packed f16 pairs (1 dword/step).
// ---------------------------------------------------------------------------
template<bool HOFF>
__global__ __attribute__((amdgpu_waves_per_eu(1, 1))) __launch_bounds__(64)
void lstm_scan_kernel(const unsigned* __restrict__ pre2h,
                      const float* __restrict__ l2_bi, const float* __restrict__ l2_bf,
                      const float* __restrict__ l2_bc, const float* __restrict__ l2_bo,
                      const float* __restrict__ bout,
                      float* __restrict__ h2buf, float* __restrict__ out) {
    const int tid = threadIdx.x;
    const int b   = blockIdx.x;
    const int lc  = (tid < 50) ? tid : 49;   // lanes 50..63 compute junk, never read
    const int uu  = lc >> 1;
    const bool odd = (tid & 1);

    // pass-B activation per parity: even lane -> tanh form, odd -> sigmoid
    const float tA = odd ? 1.0f : 2.0f;
    const float tC = odd ? 0.0f : -1.0f;
    const float b2A = (odd ? l2_bf[uu] : l2_bi[uu]) * (-L2E);
    const float b2B = odd ? (l2_bo[uu] * (-L2E)) : (l2_bc[uu] * (-2.0f * L2E));
    const float boutv = bout[0];

    // weights: f16 pairs PINNED in VGPRs (78 u32)
    #define LW(i) const unsigned w1A_##i = ldpin(g_w1 + (i)*100 + lc);      \
                  const unsigned w1B_##i = ldpin(g_w1 + (i)*100 + 50 + lc); \
                  const unsigned wxA_##i = ldpin(g_wx + (i)*100 + lc);      \
                  const unsigned wxB_##i = ldpin(g_wx + (i)*100 + 50 + lc); \
                  const unsigned whA_##i = ldpin(g_wh + (i)*100 + lc);      \
                  const unsigned whB_##i = ldpin(g_wh + (i)*100 + 50 + lc);
    R13(LW)
    #undef LW
    #define LWO(i) const unsigned wo_##i = HOFF ? 0u : g_wo[i];
    R13(LWO)
    #undef LWO

    // h broadcasts: packed f16 unit-pairs in SGPRs (readlane dest)
    #define DH(i) unsigned s1_##i = 0u, s2_##i = 0u;
    R13(DH)
    #undef DH
    float c1 = 0.f, c2 = 0.f;

    const unsigned* prow = pre2h + (size_t)b * SEQ * 50 + lc;
    float* h2p = HOFF ? (h2buf + (size_t)b * SEQ * UNITS + uu) : nullptr;
    const bool st = (tid < 50) && !odd;

    // carried F1 accumulators, primed from pre(0) (h1(-1)=0)
    const unsigned p0 = prow[0];
    float aA = lo16(p0), aB = hi16(p0);
    unsigned q1 = prow[50], q2 = prow[100], q3 = prow[150];

    auto step = [&](unsigned pw, int t) {
        // ---- layer-1 activations from carried (pre-scaled) dot
        const float avA = sig_raw(aA);                        // i (even) / f (odd)
        const float avB = fmaf(tA, sig_raw(aB), tC);          // g / o
        const float fv = dswap(avA);
        const float ov = dswap(avB);
        c1 = fmaf(avB, avA, fv * c1);                         // even lanes valid
        const float h1v = ov * tanh5(c1);
        const unsigned m1 = pk16(h1v, dpp2(h1v));             // (h[2q], h[2q+1])
        #define BC1(i) s1_##i = rdlu(m1, 4 * (i));
        R13(BC1)
        #undef BC1
        // ---- interleaved dots: F2(t) + F1(t+1); naA/naB seeded from f16 pre
        float naA = lo16(pw), naB = hi16(pw);
        float xA = b2A, xB = b2B, hA = 0.f, hB = 0.f;
        #define DD(i) xA  = fdot2_(wxA_##i, s1_##i, xA);  \
                      xB  = fdot2_(wxB_##i, s1_##i, xB);  \
                      hA  = fdot2_(whA_##i, s2_##i, hA);  \
                      hB  = fdot2_(whB_##i, s2_##i, hB);  \
                      naA = fdot2_(w1A_##i, s1_##i, naA); \
                      naB = fdot2_(w1B_##i, s1_##i, naB);
        R13(DD)
        #undef DD
        // ---- layer-2 activations + state
        const float avA2 = sig_raw(xA + hA);
        const float avB2 = fmaf(tA, sig_raw(xB + hB), tC);
        const float fv2 = dswap(avA2);
        const float ov2 = dswap(avB2);
        c2 = fmaf(avB2, avA2, fv2 * c2);
        const float h2v = ov2 * tanh5(c2);
        if (HOFF) {
            if (st) h2p[(size_t)t * UNITS] = h2v;
        }
        const unsigned m2 = pk16(h2v, dpp2(h2v));
        #define BC2(i) s2_##i = rdlu(m2, 4 * (i));
        R13(BC2)
        #undef BC2
        if (!HOFF) {
            float hp = boutv;
            #define HH(i) hp = fdot2_(wo_##i, s2_##i, hp);
            R13(HH)
            #undef HH
            if (tid == 0) out[(size_t)b * SEQ + t] = sig_raw(-L2E * hp);
        }
        aA = naA; aB = naB;
    };

    #pragma unroll 1
    for (int g = 0; g < SEQ / 4; ++g) {
        // prefetch rows 4(g+1)..4(g+1)+3 (clamped; tail value never used)
        const int rb = (g < SEQ / 4 - 1) ? 4 * (g + 1) : (SEQ - 4);
        const unsigned* pg = prow + (size_t)rb * 50;
        const unsigned n0 = pg[0], n1 = pg[50], n2 = pg[100], n3 = pg[150];
        const int t = 4 * g;
        step(q1, t);
        step(q2, t + 1);
        step(q3, t + 2);
        step(n0, t + 3);
        q1 = n1; q2 = n2; q3 = n3;
    }
}

// ---------------------------------------------------------------------------
__global__ __launch_bounds__(256)
void head_kernel(const float* __restrict__ h2buf, const float* __restrict__ Wout,
                 const float* __restrict__ bout, float* __restrict__ out) {
    __shared__ float wl[26];
    if (threadIdx.x < 25) wl[threadIdx.x] = Wout[threadIdx.x];
    if (threadIdx.x == 25) wl[25] = bout[0];
    __syncthreads();
    const int r = blockIdx.x * 256 + threadIdx.x;     // grid exactly covers BT
    const float* hp = h2buf + (size_t)r * UNITS;
    float p0 = wl[25], p1 = 0.f;
    #pragma unroll
    for (int k = 0; k < UNITS; ++k) {
        if (k & 1) p1 = fmaf(hp[k], wl[k], p1);
        else       p0 = fmaf(hp[k], wl[k], p0);
    }
    out[r] = sig_raw(-L2E * (p0 + p1));
}

// ---------------------------------------------------------------------------
extern "C" void kernel_launch(void* const* d_in, const int* in_sizes, int n_in,
                              void* d_out, int out_size, void* d_ws, size_t ws_size,
                              hipStream_t stream) {
    const float* x      = (const float*)d_in[0];
    const float* Wout   = (const float*)d_in[1];
    const float* bout   = (const float*)d_in[2];
    const float* l1_Wxi = (const float*)d_in[3];
    const float* l1_bi  = (const float*)d_in[4];
    const float* l1_Whi = (const float*)d_in[5];
    const float* l1_Wxf = (const float*)d_in[6];
    const float* l1_bf  = (const float*)d_in[7];
    const float* l1_Whf = (const float*)d_in[8];
    const float* l1_Wxc = (const float*)d_in[9];
    const float* l1_bc  = (const float*)d_in[10];
    const float* l1_Whc = (const float*)d_in[11];
    const float* l1_Wxo = (const float*)d_in[12];
    const float* l1_bo  = (const float*)d_in[13];
    const float* l1_Who = (const float*)d_in[14];
    const float* l2_Wxi = (const float*)d_in[15];
    const float* l2_bi  = (const float*)d_in[16];
    const float* l2_Whi = (const float*)d_in[17];
    const float* l2_Wxf = (const float*)d_in[18];
    const float* l2_bf  = (const float*)d_in[19];
    const float* l2_Whf = (const float*)d_in[20];
    const float* l2_Wxc = (const float*)d_in[21];
    const float* l2_bc  = (const float*)d_in[22];
    const float* l2_Whc = (const float*)d_in[23];
    const float* l2_Wxo = (const float*)d_in[24];
    const float* l2_bo  = (const float*)d_in[25];
    const float* l2_Who = (const float*)d_in[26];
    float* out = (float*)d_out;

    const size_t pre_bytes = (size_t)BT * 50 * sizeof(unsigned);  // 105 MB
    const size_t h2_bytes  = (size_t)BT * UNITS * sizeof(float);  // 52.4 MB
    unsigned* pre2h = (unsigned*)d_ws;

    prep_kernel<<<1, 128, 0, stream>>>(
        l1_Whi, l1_Whf, l1_Whc, l1_Who,
        l1_Wxi, l1_Wxf, l1_Wxc, l1_Wxo,
        l1_bi, l1_bf, l1_bc, l1_bo,
        l2_Wxi, l2_Wxf, l2_Wxc, l2_Wxo,
        l2_Whi, l2_Whf, l2_Whc, l2_Who,
        Wout);
    proj_kernel<<<BT / 512, 256, 0, stream>>>(x, pre2h);

    if (ws_size >= pre_bytes + h2_bytes) {
        float* h2buf = (float*)((char*)d_ws + pre_bytes);
        lstm_scan_kernel<true><<<BATCH, 64, 0, stream>>>(
            pre2h, l2_bi, l2_bf, l2_bc, l2_bo, bout, h2buf, out);
        head_kernel<<<BT / 256, 256, 0, stream>>>(h2buf, Wout, bout, out);
    } else {
        lstm_scan_kernel<false><<<BATCH, 64, 0, stream>>>(
            pre2h, l2_bi, l2_bf, l2_bc, l2_bo, bout, nullptr, out);
    }
}